// Round 1
// baseline (6286.026 us; speedup 1.0000x reference)
//
#include <hip/hip_runtime.h>
#include <hip/hip_bf16.h>
#include <math.h>

#define NNODES 65536
#define NEDGES 1048576
#define NGRAPHS 64

// ---- order-preserving float<->uint encoding for atomicMax-based max ----
__device__ __forceinline__ unsigned encf(float f) {
    unsigned u = __float_as_uint(f);
    return (u & 0x80000000u) ? ~u : (u | 0x80000000u);
}
__device__ __forceinline__ float decf(unsigned u) {
    unsigned v = (u & 0x80000000u) ? (u & 0x7FFFFFFFu) : ~u;
    return __uint_as_float(v);
}
#define ENC_NEG_INF 0x007FFFFFu   // encf(-inf)

// ============================ CSR build ============================
__global__ void k_init(int* deg, int* cursor, unsigned* poolEnc) {
    int i = blockIdx.x * 256 + threadIdx.x;
    if (i < NNODES) { deg[i] = 0; cursor[i] = 0; }
    if (i < NGRAPHS * 256) poolEnc[i] = ENC_NEG_INF;
}

__global__ void k_count(const int* __restrict__ ei, int* deg) {
    int e = blockIdx.x * 256 + threadIdx.x;
    atomicAdd(&deg[ei[NEDGES + e]], 1);
}

__global__ void k_scan1(const int* __restrict__ deg, int* rowptr, int* bsum) {
    __shared__ int s[256];
    int t = threadIdx.x, b = blockIdx.x;
    int v = deg[b * 256 + t];
    s[t] = v;
    __syncthreads();
    for (int off = 1; off < 256; off <<= 1) {
        int x = (t >= off) ? s[t - off] : 0;
        __syncthreads();
        if (t >= off) s[t] += x;
        __syncthreads();
    }
    rowptr[b * 256 + t] = s[t] - v;       // local exclusive
    if (t == 255) bsum[b] = s[255];
}

__global__ void k_scan2(const int* __restrict__ bsum, int* boff) {
    __shared__ int s[256];
    int t = threadIdx.x;
    int v = bsum[t];
    s[t] = v;
    __syncthreads();
    for (int off = 1; off < 256; off <<= 1) {
        int x = (t >= off) ? s[t - off] : 0;
        __syncthreads();
        if (t >= off) s[t] += x;
        __syncthreads();
    }
    boff[t] = s[t] - v;                   // exclusive block offsets
}

__global__ void k_scan3(int* rowptr, const int* __restrict__ boff) {
    int i = blockIdx.x * 256 + threadIdx.x;
    rowptr[i] += boff[blockIdx.x];
    if (i == 0) rowptr[NNODES] = NEDGES;
}

__global__ void k_scatter(const int* __restrict__ ei, const int* __restrict__ rowptr,
                          int* cursor, int* csr_src, int* csr_dst) {
    int e = blockIdx.x * 256 + threadIdx.x;
    int s = ei[e], d = ei[NEDGES + e];
    int pos = rowptr[d] + atomicAdd(&cursor[d], 1);
    csr_src[pos] = s;
    csr_dst[pos] = d;
}

// ============================ U/V precompute ============================
// U[i] = X[i] @ (W1_top - W1_bot) + b1 ;  V[i] = X[i] @ W1_bot
template <int FIN, int H>
__global__ __launch_bounds__(256) void k_uv(const float* __restrict__ X,
                                            const float* __restrict__ W1,
                                            const float* __restrict__ B1,
                                            float* __restrict__ U, float* __restrict__ V) {
    constexpr int NPT = (16 * H) / 256;   // nodes per thread
    __shared__ float xs[16][FIN];
    int tid = threadIdx.x;
    int n0 = blockIdx.x * 16;
    for (int idx = tid; idx < 16 * FIN; idx += 256)
        xs[idx / FIN][idx % FIN] = X[(size_t)(n0 + idx / FIN) * FIN + (idx % FIN)];
    __syncthreads();
    int h = tid & (H - 1);
    int nb = (tid / H) * NPT;
    float u[NPT], v[NPT];
    float bb = B1[h];
#pragma unroll
    for (int n = 0; n < NPT; n++) { u[n] = bb; v[n] = 0.f; }
    for (int f = 0; f < FIN; f++) {
        float wt = W1[f * H + h];
        float wb = W1[(FIN + f) * H + h];
        float wd = wt - wb;
#pragma unroll
        for (int n = 0; n < NPT; n++) {
            float xv = xs[nb + n][f];
            u[n] += xv * wd;
            v[n] += xv * wb;
        }
    }
#pragma unroll
    for (int n = 0; n < NPT; n++) {
        U[(size_t)(n0 + nb + n) * H + h] = u[n];
        V[(size_t)(n0 + nb + n) * H + h] = v[n];
    }
}

// ============================ fused edge-GEMM + segment-max ============================
// Block owns 16 dst nodes and ALL their in-edges (CSR) -> no global atomics.
template <int H, int F, int COLS, int CPT>
__global__ __launch_bounds__(512) void k_agg(const float* __restrict__ U,
                                             const float* __restrict__ V,
                                             const float* __restrict__ W2,
                                             const float* __restrict__ B2,
                                             const int* __restrict__ rowptr,
                                             const int* __restrict__ csr_src,
                                             const int* __restrict__ csr_dst,
                                             float* __restrict__ Y) {
    constexpr int TR = 32;                 // edge-tile rows
    constexpr int TSTR = TR + 8;           // 40-float stride: 16B-aligned float4 rows
    constexpr int CT = COLS / CPT;         // 64 col-threads
    constexpr int G = 512 / CT;            // 8 row groups
    constexpr int RPT = TR / G;            // 4 rows/thread
    constexpr int LOG2H = (H == 64) ? 6 : ((H == 128) ? 7 : 8);
    static_assert(CT == 64 && G == 8 && RPT == 4, "layout");

    __shared__ __hip_bfloat16 w2s[H * COLS];
    __shared__ __align__(16) float ts[H * TSTR];
    __shared__ unsigned accs[16 * COLS];
    __shared__ int slotA[TR], srcA[TR];

    int tid = threadIdx.x;
    int n0 = blockIdx.x * 16;
    int colbase = blockIdx.y * COLS;

    for (int idx = tid; idx < H * COLS; idx += 512) {
        int h = idx / COLS, cc = idx % COLS;
        w2s[idx] = __float2bfloat16(W2[h * F + colbase + cc]);
    }
    for (int idx = tid; idx < 16 * COLS; idx += 512) accs[idx] = ENC_NEG_INF;

    int e0 = rowptr[n0], e1 = rowptr[n0 + 16];
    int c = tid & 63;
    int g = tid >> 6;
    __syncthreads();

    for (int base = e0; base < e1; base += TR) {
        if (tid < TR) {
            int p = base + tid;
            if (p < e1) { slotA[tid] = csr_dst[p] - n0; srcA[tid] = csr_src[p]; }
            else        { slotA[tid] = -1;              srcA[tid] = 0; }
        }
        __syncthreads();
        // hidden tile t[h][r] = relu(U[dst,h] + V[src,h])
        for (int idx = tid; idx < TR * H; idx += 512) {
            int h = idx & (H - 1);
            int r = idx >> LOG2H;
            float tv = 0.f;
            int sl = slotA[r];
            if (sl >= 0) {
                float uu = U[(size_t)(n0 + sl) * H + h];
                float vv = V[(size_t)srcA[r] * H + h];
                tv = fmaxf(uu + vv, 0.f);
            }
            ts[h * TSTR + r] = tv;
        }
        __syncthreads();
        // GEMM: 4 rows x CPT cols per thread, t read is wave-broadcast b128
        float a0[RPT] = {0.f, 0.f, 0.f, 0.f};
        float a1[RPT] = {0.f, 0.f, 0.f, 0.f};
#pragma unroll 8
        for (int h = 0; h < H; h++) {
            const float4 tv = *(const float4*)&ts[h * TSTR + g * RPT];
            float w0 = __bfloat162float(w2s[h * COLS + c]);
            a0[0] += tv.x * w0; a0[1] += tv.y * w0;
            a0[2] += tv.z * w0; a0[3] += tv.w * w0;
            if (CPT == 2) {
                float w1v = __bfloat162float(w2s[h * COLS + c + 64]);
                a1[0] += tv.x * w1v; a1[1] += tv.y * w1v;
                a1[2] += tv.z * w1v; a1[3] += tv.w * w1v;
            }
        }
        // segmented max into LDS accumulator (encoded atomicMax, shared scope)
#pragma unroll
        for (int r = 0; r < RPT; r++) {
            int sl = slotA[g * RPT + r];
            if (sl >= 0) {
                atomicMax(&accs[sl * COLS + c], encf(a0[r]));
                if (CPT == 2) atomicMax(&accs[sl * COLS + c + 64], encf(a1[r]));
            }
        }
        __syncthreads();
    }
    for (int idx = tid; idx < 16 * COLS; idx += 512) {
        int sl = idx / COLS, cc = idx % COLS;
        float m = decf(accs[idx]);
        float o = isfinite(m) ? (m + B2[colbase + cc]) : 0.f;   // empty segment -> 0
        Y[(size_t)(n0 + sl) * F + colbase + cc] = o;
    }
}

// ============================ global max-pool + FC ============================
__global__ void k_pool(const float* __restrict__ X3, const int* __restrict__ batch,
                       unsigned* poolEnc) {
    int gph = blockIdx.x;
    int seg = blockIdx.y;
    int c = threadIdx.x;
    int lo = 0, hi = NNODES;
    while (lo < hi) { int mid = (lo + hi) >> 1; if (batch[mid] < gph) lo = mid + 1; else hi = mid; }
    int start = lo;
    hi = NNODES;
    while (lo < hi) { int mid = (lo + hi) >> 1; if (batch[mid] < gph + 1) lo = mid + 1; else hi = mid; }
    int end = lo;
    int chunk = (end - start + 7) >> 3;
    int s = start + seg * chunk;
    int e = min(end, s + chunk);
    float m = -INFINITY;
    for (int n = s; n < e; n++) m = fmaxf(m, X3[(size_t)n * 256 + c]);
    atomicMax(&poolEnc[gph * 256 + c], encf(m));
}

__global__ __launch_bounds__(128) void k_fc(const unsigned* __restrict__ poolEnc,
                                            const float* __restrict__ Wfc,
                                            const float* __restrict__ Bfc,
                                            float* __restrict__ out) {
    __shared__ float p[256];
    int gph = blockIdx.x, c = threadIdx.x;
    for (int k = c; k < 256; k += 128) {
        float m = decf(poolEnc[gph * 256 + k]);
        p[k] = isfinite(m) ? m : 0.f;
    }
    __syncthreads();
    float s = Bfc[c];
    for (int k = 0; k < 256; k++) s += p[k] * Wfc[k * 128 + c];
    out[gph * 128 + c] = s;
}

// ============================ launch ============================
extern "C" void kernel_launch(void* const* d_in, const int* in_sizes, int n_in,
                              void* d_out, int out_size, void* d_ws, size_t ws_size,
                              hipStream_t stream) {
    const float* x     = (const float*)d_in[0];
    const int*   ei    = (const int*)d_in[1];
    const int*   batch = (const int*)d_in[2];
    const float* w1_1 = (const float*)d_in[3];
    const float* b1_1 = (const float*)d_in[4];
    const float* w2_1 = (const float*)d_in[5];
    const float* b2_1 = (const float*)d_in[6];
    const float* w1_2 = (const float*)d_in[7];
    const float* b1_2 = (const float*)d_in[8];
    const float* w2_2 = (const float*)d_in[9];
    const float* b2_2 = (const float*)d_in[10];
    const float* w1_3 = (const float*)d_in[11];
    const float* b1_3 = (const float*)d_in[12];
    const float* w2_3 = (const float*)d_in[13];
    const float* b2_3 = (const float*)d_in[14];
    const float* wfc  = (const float*)d_in[15];
    const float* bfc  = (const float*)d_in[16];
    float* out = (float*)d_out;

    char* ws = (char*)d_ws;
    size_t off = 0;
    auto alloc = [&](size_t bytes) {
        void* p = ws + off;
        off = (off + bytes + 255) & ~(size_t)255;
        return p;
    };
    int* deg      = (int*)alloc((size_t)NNODES * 4);
    int* cursor   = (int*)alloc((size_t)NNODES * 4);
    int* rowptr   = (int*)alloc((size_t)(NNODES + 1) * 4);
    int* bsum     = (int*)alloc(256 * 4);
    int* boff     = (int*)alloc(256 * 4);
    int* csr_src  = (int*)alloc((size_t)NEDGES * 4);
    int* csr_dst  = (int*)alloc((size_t)NEDGES * 4);
    float* U      = (float*)alloc((size_t)NNODES * 256 * 4);
    float* V      = (float*)alloc((size_t)NNODES * 256 * 4);
    float* x1     = (float*)alloc((size_t)NNODES * 64 * 4);
    float* x2     = (float*)alloc((size_t)NNODES * 128 * 4);
    float* x3     = (float*)alloc((size_t)NNODES * 256 * 4);
    unsigned* poolEnc = (unsigned*)alloc((size_t)NGRAPHS * 256 * 4);
    (void)ws_size; (void)in_sizes; (void)n_in; (void)out_size;

    // CSR by dst (shared across the 3 layers)
    k_init<<<256, 256, 0, stream>>>(deg, cursor, poolEnc);
    k_count<<<NEDGES / 256, 256, 0, stream>>>(ei, deg);
    k_scan1<<<256, 256, 0, stream>>>(deg, rowptr, bsum);
    k_scan2<<<1, 256, 0, stream>>>(bsum, boff);
    k_scan3<<<256, 256, 0, stream>>>(rowptr, boff);
    k_scatter<<<NEDGES / 256, 256, 0, stream>>>(ei, rowptr, cursor, csr_src, csr_dst);

    // layer 1: F_in=3, H=64, F=64
    k_uv<3, 64><<<NNODES / 16, 256, 0, stream>>>(x, w1_1, b1_1, U, V);
    k_agg<64, 64, 64, 1><<<dim3(NNODES / 16, 1), 512, 0, stream>>>(U, V, w2_1, b2_1, rowptr, csr_src, csr_dst, x1);
    // layer 2: F_in=64, H=128, F=128
    k_uv<64, 128><<<NNODES / 16, 256, 0, stream>>>(x1, w1_2, b1_2, U, V);
    k_agg<128, 128, 128, 2><<<dim3(NNODES / 16, 1), 512, 0, stream>>>(U, V, w2_2, b2_2, rowptr, csr_src, csr_dst, x2);
    // layer 3: F_in=128, H=256, F=256 (two column halves)
    k_uv<128, 256><<<NNODES / 16, 256, 0, stream>>>(x2, w1_3, b1_3, U, V);
    k_agg<256, 256, 128, 2><<<dim3(NNODES / 16, 2), 512, 0, stream>>>(U, V, w2_3, b2_3, rowptr, csr_src, csr_dst, x3);

    // global max pool + FC
    k_pool<<<dim3(NGRAPHS, 8), 256, 0, stream>>>(x3, batch, poolEnc);
    k_fc<<<NGRAPHS, 128, 0, stream>>>(poolEnc, wfc, bfc, out);
}

// Round 2
// 2228.301 us; speedup vs baseline: 2.8210x; 2.8210x over previous
//
#include <hip/hip_runtime.h>
#include <hip/hip_bf16.h>
#include <math.h>

#define NNODES 65536
#define NEDGES 1048576
#define NGRAPHS 64

typedef __attribute__((ext_vector_type(8))) short short8;
typedef __attribute__((ext_vector_type(4))) float f32x4;

// ---- order-preserving float<->uint encoding for atomicMax-based max ----
__device__ __forceinline__ unsigned encf(float f) {
    unsigned u = __float_as_uint(f);
    return (u & 0x80000000u) ? ~u : (u | 0x80000000u);
}
__device__ __forceinline__ float decf(unsigned u) {
    unsigned v = (u & 0x80000000u) ? (u & 0x7FFFFFFFu) : ~u;
    return __uint_as_float(v);
}
#define ENC_NEG_INF 0x007FFFFFu   // encf(-inf)

// RNE float -> bf16 bits (weights/activations are finite; no NaN handling needed)
__device__ __forceinline__ unsigned bfbits(float f) {
    unsigned u = __float_as_uint(f);
    return (u + 0x7FFFu + ((u >> 16) & 1u)) >> 16;
}
__device__ __forceinline__ unsigned pk2(float a, float b) {
    return bfbits(a) | (bfbits(b) << 16);
}

// ============================ CSR build ============================
__global__ void k_init(int* deg, int* cursor, unsigned* poolEnc) {
    int i = blockIdx.x * 256 + threadIdx.x;
    if (i < NNODES) { deg[i] = 0; cursor[i] = 0; }
    if (i < NGRAPHS * 256) poolEnc[i] = ENC_NEG_INF;
}

__global__ void k_count(const int* __restrict__ ei, int* deg) {
    int e = blockIdx.x * 256 + threadIdx.x;
    atomicAdd(&deg[ei[NEDGES + e]], 1);
}

__global__ void k_scan1(const int* __restrict__ deg, int* rowptr, int* bsum) {
    __shared__ int s[256];
    int t = threadIdx.x, b = blockIdx.x;
    int v = deg[b * 256 + t];
    s[t] = v;
    __syncthreads();
    for (int off = 1; off < 256; off <<= 1) {
        int x = (t >= off) ? s[t - off] : 0;
        __syncthreads();
        if (t >= off) s[t] += x;
        __syncthreads();
    }
    rowptr[b * 256 + t] = s[t] - v;       // local exclusive
    if (t == 255) bsum[b] = s[255];
}

__global__ void k_scan2(const int* __restrict__ bsum, int* boff) {
    __shared__ int s[256];
    int t = threadIdx.x;
    int v = bsum[t];
    s[t] = v;
    __syncthreads();
    for (int off = 1; off < 256; off <<= 1) {
        int x = (t >= off) ? s[t - off] : 0;
        __syncthreads();
        if (t >= off) s[t] += x;
        __syncthreads();
    }
    boff[t] = s[t] - v;                   // exclusive block offsets
}

__global__ void k_scan3(int* rowptr, const int* __restrict__ boff) {
    int i = blockIdx.x * 256 + threadIdx.x;
    rowptr[i] += boff[blockIdx.x];
    if (i == 0) rowptr[NNODES] = NEDGES;
}

__global__ void k_scatter(const int* __restrict__ ei, const int* __restrict__ rowptr,
                          int* cursor, int* csr_src, int* csr_dst) {
    int e = blockIdx.x * 256 + threadIdx.x;
    int s = ei[e], d = ei[NEDGES + e];
    int pos = rowptr[d] + atomicAdd(&cursor[d], 1);
    csr_src[pos] = s;
    csr_dst[pos] = d;
}

// ============================ U/V precompute ============================
// U[i] = X[i] @ (W1_top - W1_bot) + b1 ;  V[i] = X[i] @ W1_bot
template <int FIN, int H>
__global__ __launch_bounds__(256) void k_uv(const float* __restrict__ X,
                                            const float* __restrict__ W1,
                                            const float* __restrict__ B1,
                                            float* __restrict__ U, float* __restrict__ V) {
    constexpr int NPT = (16 * H) / 256;   // nodes per thread
    __shared__ float xs[16][FIN];
    int tid = threadIdx.x;
    int n0 = blockIdx.x * 16;
    for (int idx = tid; idx < 16 * FIN; idx += 256)
        xs[idx / FIN][idx % FIN] = X[(size_t)(n0 + idx / FIN) * FIN + (idx % FIN)];
    __syncthreads();
    int h = tid & (H - 1);
    int nb = (tid / H) * NPT;
    float u[NPT], v[NPT];
    float bb = B1[h];
#pragma unroll
    for (int n = 0; n < NPT; n++) { u[n] = bb; v[n] = 0.f; }
    for (int f = 0; f < FIN; f++) {
        float wt = W1[f * H + h];
        float wb = W1[(FIN + f) * H + h];
        float wd = wt - wb;
#pragma unroll
        for (int n = 0; n < NPT; n++) {
            float xv = xs[nb + n][f];
            u[n] += xv * wd;
            v[n] += xv * wb;
        }
    }
#pragma unroll
    for (int n = 0; n < NPT; n++) {
        U[(size_t)(n0 + nb + n) * H + h] = u[n];
        V[(size_t)(n0 + nb + n) * H + h] = v[n];
    }
}

// ================= fused edge-GEMM (MFMA bf16) + segment-max =================
// Block (256 thr = 4 waves) owns 16 dst nodes + all their in-edges (CSR).
// Edge tile TR=64 rows. Waves: 2-way row split x 2-way col split.
// W2 fragments held in registers for the whole kernel; only A (hidden) comes
// from LDS per K-step. Segment-max merges slot-runs in registers, then LDS
// atomicMax; CSR ordering makes slots non-decreasing within a tile.
template <int H, int F, int COLS>
__global__ __launch_bounds__(256, 2) void k_agg(const float* __restrict__ U,
                                                const float* __restrict__ V,
                                                const float* __restrict__ W2,
                                                const float* __restrict__ B2,
                                                const int* __restrict__ rowptr,
                                                const int* __restrict__ csr_src,
                                                const int* __restrict__ csr_dst,
                                                float* __restrict__ Y) {
    constexpr int TR = 64;                  // edge rows per tile
    constexpr int HP = H + 8;               // padded hidden row (bf16 units): 16B-aligned frags, 2-way bank alias only
    constexpr int NT = (COLS / 2) / 16;     // n-tiles per wave
    constexpr int KS = H / 32;              // k-steps
    constexpr int ACCSTR = COLS + 1;        // bank-spread accumulator stride
    constexpr int LPR = H / 4;              // threads per hidden row (construction)
    constexpr int RPP = 256 / LPR;          // rows per construction pass
    static_assert(H % 32 == 0 && COLS % 32 == 0 && LPR <= 256, "shape");

    __shared__ unsigned short hs[TR * HP];          // hidden tile, bf16
    __shared__ unsigned accs[16 * ACCSTR];          // per-slot running max (encoded)
    __shared__ int srcA[TR];
    __shared__ signed char slotB[TR];

    int tid = threadIdx.x;
    int n0 = blockIdx.x * 16;
    int colbase = blockIdx.y * COLS;

    int ln = tid & 15;              // MFMA n / m lane index
    int qd = (tid >> 4) & 3;        // MFMA quad
    int wv = tid >> 6;
    int rw = wv >> 1;               // row half (0: rows 0-31, 1: rows 32-63)
    int cw = wv & 1;                // col half

    // ---- load W2 fragments into registers (bf16), once ----
    short8 Bf[NT][KS];
#pragma unroll
    for (int nt = 0; nt < NT; nt++) {
        int col = colbase + cw * (COLS / 2) + nt * 16 + ln;
#pragma unroll
        for (int ks = 0; ks < KS; ks++) {
            int kb = ks * 32 + qd * 8;
            short8 b;
#pragma unroll
            for (int j = 0; j < 8; j++)
                b[j] = (short)bfbits(W2[(size_t)(kb + j) * F + col]);
            Bf[nt][ks] = b;
        }
    }

    for (int idx = tid; idx < 16 * ACCSTR; idx += 256) accs[idx] = ENC_NEG_INF;

    int e0 = rowptr[n0], e1 = rowptr[n0 + 16];

    int rid = tid / LPR;            // construction: my first row
    int kk = (tid % LPR) * 4;       // construction: my 4-col chunk

    for (int base = e0; base < e1; base += TR) {
        __syncthreads();            // prev tile fully consumed (hs reads + atomics done)
        if (tid < TR) {
            int p = base + tid;
            if (p < e1) { srcA[tid] = csr_src[p]; slotB[tid] = (signed char)(csr_dst[p] - n0); }
            else        { srcA[tid] = 0;          slotB[tid] = -1; }
        }
        __syncthreads();

        // ---- build hidden tile: hs[r][k] = bf16(relu(U[dst,k] + V[src,k])) ----
        for (int r = rid; r < TR; r += RPP) {
            int sl = slotB[r];
            uint2 w;
            if (sl >= 0) {
                int src = srcA[r];
                const float4 u4 = *(const float4*)&U[(size_t)(n0 + sl) * H + kk];
                const float4 v4 = *(const float4*)&V[(size_t)src * H + kk];
                w.x = pk2(fmaxf(u4.x + v4.x, 0.f), fmaxf(u4.y + v4.y, 0.f));
                w.y = pk2(fmaxf(u4.z + v4.z, 0.f), fmaxf(u4.w + v4.w, 0.f));
            } else {
                w.x = 0u; w.y = 0u;
            }
            *(uint2*)&hs[r * HP + kk] = w;
        }
        __syncthreads();

        // ---- MFMA: [32 rows x COLS/2 cols] per wave ----
        f32x4 acc[2][NT];
#pragma unroll
        for (int mt = 0; mt < 2; mt++)
#pragma unroll
            for (int nt = 0; nt < NT; nt++)
                acc[mt][nt] = (f32x4){0.f, 0.f, 0.f, 0.f};

#pragma unroll
        for (int ks = 0; ks < KS; ks++) {
            int ko = ks * 32 + qd * 8;
            short8 a0 = *(const short8*)&hs[(rw * 32 + ln) * HP + ko];
            short8 a1 = *(const short8*)&hs[(rw * 32 + 16 + ln) * HP + ko];
#pragma unroll
            for (int nt = 0; nt < NT; nt++) {
                acc[0][nt] = __builtin_amdgcn_mfma_f32_16x16x32_bf16(a0, Bf[nt][ks], acc[0][nt], 0, 0, 0);
                acc[1][nt] = __builtin_amdgcn_mfma_f32_16x16x32_bf16(a1, Bf[nt][ks], acc[1][nt], 0, 0, 0);
            }
        }

        // ---- segmented max: merge slot-runs in registers, then LDS atomicMax ----
#pragma unroll
        for (int mt = 0; mt < 2; mt++) {
            int rbase = rw * 32 + mt * 16 + qd * 4;
            char4 ss = *(const char4*)&slotB[rbase];
#pragma unroll
            for (int nt = 0; nt < NT; nt++) {
                int colw = cw * (COLS / 2) + nt * 16 + ln;
                float c0 = acc[mt][nt][0], c1 = acc[mt][nt][1];
                float c2 = acc[mt][nt][2], c3 = acc[mt][nt][3];
                float m3 = c3;
                float m2 = (ss.z == ss.w) ? fmaxf(c2, m3) : c2;
                float m1 = (ss.y == ss.z) ? fmaxf(c1, m2) : c1;
                float m0 = (ss.x == ss.y) ? fmaxf(c0, m1) : c0;
                if (ss.x >= 0)              atomicMax(&accs[(int)ss.x * ACCSTR + colw], encf(m0));
                if (ss.y >= 0 && ss.y != ss.x) atomicMax(&accs[(int)ss.y * ACCSTR + colw], encf(m1));
                if (ss.z >= 0 && ss.z != ss.y) atomicMax(&accs[(int)ss.z * ACCSTR + colw], encf(m2));
                if (ss.w >= 0 && ss.w != ss.z) atomicMax(&accs[(int)ss.w * ACCSTR + colw], encf(m3));
            }
        }
    }
    __syncthreads();

    for (int idx = tid; idx < 16 * COLS; idx += 256) {
        int sl = idx / COLS, cc = idx % COLS;
        float m = decf(accs[sl * ACCSTR + cc]);
        float o = isfinite(m) ? (m + B2[colbase + cc]) : 0.f;   // empty segment -> 0
        Y[(size_t)(n0 + sl) * F + colbase + cc] = o;
    }
}

// ============================ global max-pool + FC ============================
__global__ void k_pool(const float* __restrict__ X3, const int* __restrict__ batch,
                       unsigned* poolEnc) {
    int gph = blockIdx.x;
    int seg = blockIdx.y;
    int c = threadIdx.x;
    int lo = 0, hi = NNODES;
    while (lo < hi) { int mid = (lo + hi) >> 1; if (batch[mid] < gph) lo = mid + 1; else hi = mid; }
    int start = lo;
    hi = NNODES;
    while (lo < hi) { int mid = (lo + hi) >> 1; if (batch[mid] < gph + 1) lo = mid + 1; else hi = mid; }
    int end = lo;
    int chunk = (end - start + 7) >> 3;
    int s = start + seg * chunk;
    int e = min(end, s + chunk);
    float m = -INFINITY;
    for (int n = s; n < e; n++) m = fmaxf(m, X3[(size_t)n * 256 + c]);
    atomicMax(&poolEnc[gph * 256 + c], encf(m));
}

__global__ __launch_bounds__(128) void k_fc(const unsigned* __restrict__ poolEnc,
                                            const float* __restrict__ Wfc,
                                            const float* __restrict__ Bfc,
                                            float* __restrict__ out) {
    __shared__ float p[256];
    int gph = blockIdx.x, c = threadIdx.x;
    for (int k = c; k < 256; k += 128) {
        float m = decf(poolEnc[gph * 256 + k]);
        p[k] = isfinite(m) ? m : 0.f;
    }
    __syncthreads();
    float s = Bfc[c];
    for (int k = 0; k < 256; k++) s += p[k] * Wfc[k * 128 + c];
    out[gph * 128 + c] = s;
}

// ============================ launch ============================
extern "C" void kernel_launch(void* const* d_in, const int* in_sizes, int n_in,
                              void* d_out, int out_size, void* d_ws, size_t ws_size,
                              hipStream_t stream) {
    const float* x     = (const float*)d_in[0];
    const int*   ei    = (const int*)d_in[1];
    const int*   batch = (const int*)d_in[2];
    const float* w1_1 = (const float*)d_in[3];
    const float* b1_1 = (const float*)d_in[4];
    const float* w2_1 = (const float*)d_in[5];
    const float* b2_1 = (const float*)d_in[6];
    const float* w1_2 = (const float*)d_in[7];
    const float* b1_2 = (const float*)d_in[8];
    const float* w2_2 = (const float*)d_in[9];
    const float* b2_2 = (const float*)d_in[10];
    const float* w1_3 = (const float*)d_in[11];
    const float* b1_3 = (const float*)d_in[12];
    const float* w2_3 = (const float*)d_in[13];
    const float* b2_3 = (const float*)d_in[14];
    const float* wfc  = (const float*)d_in[15];
    const float* bfc  = (const float*)d_in[16];
    float* out = (float*)d_out;

    char* ws = (char*)d_ws;
    size_t off = 0;
    auto alloc = [&](size_t bytes) {
        void* p = ws + off;
        off = (off + bytes + 255) & ~(size_t)255;
        return p;
    };
    int* deg      = (int*)alloc((size_t)NNODES * 4);
    int* cursor   = (int*)alloc((size_t)NNODES * 4);
    int* rowptr   = (int*)alloc((size_t)(NNODES + 1) * 4);
    int* bsum     = (int*)alloc(256 * 4);
    int* boff     = (int*)alloc(256 * 4);
    int* csr_src  = (int*)alloc((size_t)NEDGES * 4);
    int* csr_dst  = (int*)alloc((size_t)NEDGES * 4);
    float* U      = (float*)alloc((size_t)NNODES * 256 * 4);
    float* V      = (float*)alloc((size_t)NNODES * 256 * 4);
    float* x1     = (float*)alloc((size_t)NNODES * 64 * 4);
    float* x2     = (float*)alloc((size_t)NNODES * 128 * 4);
    float* x3     = (float*)alloc((size_t)NNODES * 256 * 4);
    unsigned* poolEnc = (unsigned*)alloc((size_t)NGRAPHS * 256 * 4);
    (void)ws_size; (void)in_sizes; (void)n_in; (void)out_size;

    // CSR by dst (shared across the 3 layers)
    k_init<<<256, 256, 0, stream>>>(deg, cursor, poolEnc);
    k_count<<<NEDGES / 256, 256, 0, stream>>>(ei, deg);
    k_scan1<<<256, 256, 0, stream>>>(deg, rowptr, bsum);
    k_scan2<<<1, 256, 0, stream>>>(bsum, boff);
    k_scan3<<<256, 256, 0, stream>>>(rowptr, boff);
    k_scatter<<<NEDGES / 256, 256, 0, stream>>>(ei, rowptr, cursor, csr_src, csr_dst);

    // layer 1: F_in=3, H=64, F=64
    k_uv<3, 64><<<NNODES / 16, 256, 0, stream>>>(x, w1_1, b1_1, U, V);
    k_agg<64, 64, 64><<<dim3(NNODES / 16, 1), 256, 0, stream>>>(U, V, w2_1, b2_1, rowptr, csr_src, csr_dst, x1);
    // layer 2: F_in=64, H=128, F=128
    k_uv<64, 128><<<NNODES / 16, 256, 0, stream>>>(x1, w1_2, b1_2, U, V);
    k_agg<128, 128, 128><<<dim3(NNODES / 16, 1), 256, 0, stream>>>(U, V, w2_2, b2_2, rowptr, csr_src, csr_dst, x2);
    // layer 3: F_in=128, H=256, F=256 (two column halves)
    k_uv<128, 256><<<NNODES / 16, 256, 0, stream>>>(x2, w1_3, b1_3, U, V);
    k_agg<256, 256, 128><<<dim3(NNODES / 16, 2), 256, 0, stream>>>(U, V, w2_3, b2_3, rowptr, csr_src, csr_dst, x3);

    // global max pool + FC
    k_pool<<<dim3(NGRAPHS, 8), 256, 0, stream>>>(x3, batch, poolEnc);
    k_fc<<<NGRAPHS, 128, 0, stream>>>(poolEnc, wfc, bfc, out);
}

// Round 3
// 1007.819 us; speedup vs baseline: 6.2373x; 2.2110x over previous
//
#include <hip/hip_runtime.h>
#include <hip/hip_bf16.h>
#include <math.h>

#define NNODES 65536
#define NEDGES 1048576
#define NGRAPHS 64

typedef __attribute__((ext_vector_type(8))) short short8;
typedef __attribute__((ext_vector_type(4))) float f32x4;

// ---- order-preserving float<->uint encoding for atomicMax-based max ----
__device__ __forceinline__ unsigned encf(float f) {
    unsigned u = __float_as_uint(f);
    return (u & 0x80000000u) ? ~u : (u | 0x80000000u);
}
__device__ __forceinline__ float decf(unsigned u) {
    unsigned v = (u & 0x80000000u) ? (u & 0x7FFFFFFFu) : ~u;
    return __uint_as_float(v);
}
#define ENC_NEG_INF 0x007FFFFFu   // encf(-inf)

// RNE float -> bf16 bits (finite values only)
__device__ __forceinline__ unsigned bfbits(float f) {
    unsigned u = __float_as_uint(f);
    return (u + 0x7FFFu + ((u >> 16) & 1u)) >> 16;
}
__device__ __forceinline__ unsigned pk2(float a, float b) {
    return bfbits(a) | (bfbits(b) << 16);
}
__device__ __forceinline__ float bflo(unsigned p) { return __uint_as_float(p << 16); }
__device__ __forceinline__ float bfhi(unsigned p) { return __uint_as_float(p & 0xFFFF0000u); }

// ============================ CSR build ============================
__global__ void k_init(int* deg, int* cursor, unsigned* poolEnc) {
    int i = blockIdx.x * 256 + threadIdx.x;
    if (i < NNODES) { deg[i] = 0; cursor[i] = 0; }
    if (i < NGRAPHS * 256) poolEnc[i] = ENC_NEG_INF;
}

__global__ void k_count(const int* __restrict__ ei, int* deg) {
    int e = blockIdx.x * 256 + threadIdx.x;
    atomicAdd(&deg[ei[NEDGES + e]], 1);
}

__global__ void k_scan1(const int* __restrict__ deg, int* rowptr, int* bsum) {
    __shared__ int s[256];
    int t = threadIdx.x, b = blockIdx.x;
    int v = deg[b * 256 + t];
    s[t] = v;
    __syncthreads();
    for (int off = 1; off < 256; off <<= 1) {
        int x = (t >= off) ? s[t - off] : 0;
        __syncthreads();
        if (t >= off) s[t] += x;
        __syncthreads();
    }
    rowptr[b * 256 + t] = s[t] - v;       // local exclusive
    if (t == 255) bsum[b] = s[255];
}

__global__ void k_scan2(const int* __restrict__ bsum, int* boff) {
    __shared__ int s[256];
    int t = threadIdx.x;
    int v = bsum[t];
    s[t] = v;
    __syncthreads();
    for (int off = 1; off < 256; off <<= 1) {
        int x = (t >= off) ? s[t - off] : 0;
        __syncthreads();
        if (t >= off) s[t] += x;
        __syncthreads();
    }
    boff[t] = s[t] - v;                   // exclusive block offsets
}

__global__ void k_scan3(int* rowptr, const int* __restrict__ boff) {
    int i = blockIdx.x * 256 + threadIdx.x;
    rowptr[i] += boff[blockIdx.x];
    if (i == 0) rowptr[NNODES] = NEDGES;
}

__global__ void k_scatter(const int* __restrict__ ei, const int* __restrict__ rowptr,
                          int* cursor, int* csr_src, int* csr_dst) {
    int e = blockIdx.x * 256 + threadIdx.x;
    int s = ei[e], d = ei[NEDGES + e];
    int pos = rowptr[d] + atomicAdd(&cursor[d], 1);
    csr_src[pos] = s;
    csr_dst[pos] = d;
}

// ============================ U/V precompute ============================
// U[i] = X[i] @ (W1_top - W1_bot) + b1  (fp32, dst-local, L1-cached in k_agg)
// V[i] = X[i] @ W1_bot                  (bf16: the random-gathered operand)
template <int FIN, int H>
__global__ __launch_bounds__(256) void k_uv(const float* __restrict__ X,
                                            const float* __restrict__ W1,
                                            const float* __restrict__ B1,
                                            float* __restrict__ U,
                                            unsigned short* __restrict__ Vb) {
    constexpr int NPT = (16 * H) / 256;   // nodes per thread
    __shared__ float xs[16][FIN];
    int tid = threadIdx.x;
    int n0 = blockIdx.x * 16;
    for (int idx = tid; idx < 16 * FIN; idx += 256)
        xs[idx / FIN][idx % FIN] = X[(size_t)(n0 + idx / FIN) * FIN + (idx % FIN)];
    __syncthreads();
    int h = tid & (H - 1);
    int nb = (tid / H) * NPT;
    float u[NPT], v[NPT];
    float bb = B1[h];
#pragma unroll
    for (int n = 0; n < NPT; n++) { u[n] = bb; v[n] = 0.f; }
    for (int f = 0; f < FIN; f++) {
        float wt = W1[f * H + h];
        float wb = W1[(FIN + f) * H + h];
        float wd = wt - wb;
#pragma unroll
        for (int n = 0; n < NPT; n++) {
            float xv = xs[nb + n][f];
            u[n] += xv * wd;
            v[n] += xv * wb;
        }
    }
#pragma unroll
    for (int n = 0; n < NPT; n++) {
        U[(size_t)(n0 + nb + n) * H + h] = u[n];
        Vb[(size_t)(n0 + nb + n) * H + h] = (unsigned short)bfbits(v[n]);
    }
}

// ================= fused edge-GEMM (MFMA bf16) + segment-max =================
// Block owns 16 dst nodes + all their in-edges (CSR) -> no global atomics.
// RWAVES row groups x CWAVES col waves; TR = 32*RWAVES edge rows per tile.
// W2 fragments in registers (NT*KS short8 each = kept small to avoid spill);
// hidden tile built in LDS as bf16 from fp32 U (local) + bf16 V (gathered).
template <int H, int F, int RWAVES, int CWAVES, int MINW>
__global__ __launch_bounds__(RWAVES * CWAVES * 64, MINW)
void k_agg(const float* __restrict__ U,
           const unsigned short* __restrict__ Vb,
           const float* __restrict__ W2,
           const float* __restrict__ B2,
           const int* __restrict__ rowptr,
           const int* __restrict__ csr_src,
           const int* __restrict__ csr_dst,
           float* __restrict__ Y) {
    constexpr int BLOCK = RWAVES * CWAVES * 64;
    constexpr int TR = 32 * RWAVES;         // edge rows per tile
    constexpr int HP = H + 8;               // padded row (bf16 units), 16B-aligned frags
    constexpr int CPW = F / CWAVES;         // cols per wave
    constexpr int NT = CPW / 16;            // n-tiles per wave
    constexpr int KS = H / 32;              // k-steps
    constexpr int ACCSTR = F + 1;           // bank-spread accumulator stride
    constexpr int LPR = H / 8;              // threads per hidden row (8 elems each)
    constexpr int RPP = BLOCK / LPR;        // rows per construction pass
    static_assert(H % 32 == 0 && NT >= 1 && RPP >= 1, "shape");

    __shared__ unsigned short hs[TR * HP];  // hidden tile, bf16
    __shared__ unsigned accs[16 * ACCSTR];  // per-slot running max (encoded)
    __shared__ int srcA[TR];
    __shared__ signed char slotB[TR];

    int tid = threadIdx.x;
    int n0 = blockIdx.x * 16;

    int ln = tid & 15;              // MFMA n/m lane index
    int qd = (tid >> 4) & 3;        // MFMA quad
    int wv = tid >> 6;
    int rw = wv / CWAVES;           // row group
    int cw = wv % CWAVES;           // col wave

    // ---- load W2 fragments into registers (bf16), once ----
    short8 Bf[NT][KS];
#pragma unroll
    for (int nt = 0; nt < NT; nt++) {
        int col = cw * CPW + nt * 16 + ln;
#pragma unroll
        for (int ks = 0; ks < KS; ks++) {
            int kb = ks * 32 + qd * 8;
            short8 b;
#pragma unroll
            for (int j = 0; j < 8; j++)
                b[j] = (short)bfbits(W2[(size_t)(kb + j) * F + col]);
            Bf[nt][ks] = b;
        }
    }

    for (int idx = tid; idx < 16 * ACCSTR; idx += BLOCK) accs[idx] = ENC_NEG_INF;

    int e0 = rowptr[n0], e1 = rowptr[n0 + 16];

    int rid = tid / LPR;            // construction: my first row
    int kk = (tid % LPR) * 8;       // construction: my 8-elem chunk

    for (int base = e0; base < e1; base += TR) {
        __syncthreads();            // prev tile fully consumed
        if (tid < TR) {
            int p = base + tid;
            if (p < e1) { srcA[tid] = csr_src[p]; slotB[tid] = (signed char)(csr_dst[p] - n0); }
            else        { srcA[tid] = 0;          slotB[tid] = -1; }
        }
        __syncthreads();

        // ---- build hidden tile: hs[r][k] = bf16(relu(U[dst,k] + V[src,k])) ----
#pragma unroll
        for (int r0 = 0; r0 < TR; r0 += RPP) {
            int r = r0 + rid;
            if (RPP > TR || r < TR) {
                int sl = slotB[r];
                uint4 w;
                if (sl >= 0) {
                    int src = srcA[r];
                    const float4 ua = *(const float4*)&U[(size_t)(n0 + sl) * H + kk];
                    const float4 ub = *(const float4*)&U[(size_t)(n0 + sl) * H + kk + 4];
                    const uint4 vv = *(const uint4*)&Vb[(size_t)src * H + kk];
                    w.x = pk2(fmaxf(ua.x + bflo(vv.x), 0.f), fmaxf(ua.y + bfhi(vv.x), 0.f));
                    w.y = pk2(fmaxf(ua.z + bflo(vv.y), 0.f), fmaxf(ua.w + bfhi(vv.y), 0.f));
                    w.z = pk2(fmaxf(ub.x + bflo(vv.z), 0.f), fmaxf(ub.y + bfhi(vv.z), 0.f));
                    w.w = pk2(fmaxf(ub.z + bflo(vv.w), 0.f), fmaxf(ub.w + bfhi(vv.w), 0.f));
                } else {
                    w = (uint4){0u, 0u, 0u, 0u};
                }
                *(uint4*)&hs[r * HP + kk] = w;
            }
        }
        __syncthreads();

        // ---- MFMA: [32 rows x CPW cols] per wave ----
        f32x4 acc[2][NT];
#pragma unroll
        for (int mt = 0; mt < 2; mt++)
#pragma unroll
            for (int nt = 0; nt < NT; nt++)
                acc[mt][nt] = (f32x4){0.f, 0.f, 0.f, 0.f};

#pragma unroll
        for (int ks = 0; ks < KS; ks++) {
            int ko = ks * 32 + qd * 8;
            short8 a0 = *(const short8*)&hs[(rw * 32 + ln) * HP + ko];
            short8 a1 = *(const short8*)&hs[(rw * 32 + 16 + ln) * HP + ko];
#pragma unroll
            for (int nt = 0; nt < NT; nt++) {
                acc[0][nt] = __builtin_amdgcn_mfma_f32_16x16x32_bf16(a0, Bf[nt][ks], acc[0][nt], 0, 0, 0);
                acc[1][nt] = __builtin_amdgcn_mfma_f32_16x16x32_bf16(a1, Bf[nt][ks], acc[1][nt], 0, 0, 0);
            }
        }

        // ---- segmented max: merge slot-runs in registers, then LDS atomicMax ----
#pragma unroll
        for (int mt = 0; mt < 2; mt++) {
            int rbase = rw * 32 + mt * 16 + qd * 4;
            char4 ss = *(const char4*)&slotB[rbase];
#pragma unroll
            for (int nt = 0; nt < NT; nt++) {
                int colw = cw * CPW + nt * 16 + ln;
                float c0 = acc[mt][nt][0], c1 = acc[mt][nt][1];
                float c2 = acc[mt][nt][2], c3 = acc[mt][nt][3];
                float m3 = c3;
                float m2 = (ss.z == ss.w) ? fmaxf(c2, m3) : c2;
                float m1 = (ss.y == ss.z) ? fmaxf(c1, m2) : c1;
                float m0 = (ss.x == ss.y) ? fmaxf(c0, m1) : c0;
                if (ss.x >= 0)                 atomicMax(&accs[(int)ss.x * ACCSTR + colw], encf(m0));
                if (ss.y >= 0 && ss.y != ss.x) atomicMax(&accs[(int)ss.y * ACCSTR + colw], encf(m1));
                if (ss.z >= 0 && ss.z != ss.y) atomicMax(&accs[(int)ss.z * ACCSTR + colw], encf(m2));
                if (ss.w >= 0 && ss.w != ss.z) atomicMax(&accs[(int)ss.w * ACCSTR + colw], encf(m3));
            }
        }
    }
    __syncthreads();

    for (int idx = tid; idx < 16 * F; idx += BLOCK) {
        int sl = idx / F, cc = idx % F;
        float m = decf(accs[sl * ACCSTR + cc]);
        float o = isfinite(m) ? (m + B2[cc]) : 0.f;   // empty segment -> 0
        Y[(size_t)(n0 + sl) * F + cc] = o;
    }
}

// ============================ global max-pool + FC ============================
__global__ void k_pool(const float* __restrict__ X3, const int* __restrict__ batch,
                       unsigned* poolEnc) {
    int gph = blockIdx.x;
    int seg = blockIdx.y;
    int c = threadIdx.x;
    int lo = 0, hi = NNODES;
    while (lo < hi) { int mid = (lo + hi) >> 1; if (batch[mid] < gph) lo = mid + 1; else hi = mid; }
    int start = lo;
    hi = NNODES;
    while (lo < hi) { int mid = (lo + hi) >> 1; if (batch[mid] < gph + 1) lo = mid + 1; else hi = mid; }
    int end = lo;
    int chunk = (end - start + 7) >> 3;
    int s = start + seg * chunk;
    int e = min(end, s + chunk);
    float m = -INFINITY;
    for (int n = s; n < e; n++) m = fmaxf(m, X3[(size_t)n * 256 + c]);
    atomicMax(&poolEnc[gph * 256 + c], encf(m));
}

__global__ __launch_bounds__(128) void k_fc(const unsigned* __restrict__ poolEnc,
                                            const float* __restrict__ Wfc,
                                            const float* __restrict__ Bfc,
                                            float* __restrict__ out) {
    __shared__ float p[256];
    int gph = blockIdx.x, c = threadIdx.x;
    for (int k = c; k < 256; k += 128) {
        float m = decf(poolEnc[gph * 256 + k]);
        p[k] = isfinite(m) ? m : 0.f;
    }
    __syncthreads();
    float s = Bfc[c];
    for (int k = 0; k < 256; k++) s += p[k] * Wfc[k * 128 + c];
    out[gph * 128 + c] = s;
}

// ============================ launch ============================
extern "C" void kernel_launch(void* const* d_in, const int* in_sizes, int n_in,
                              void* d_out, int out_size, void* d_ws, size_t ws_size,
                              hipStream_t stream) {
    const float* x     = (const float*)d_in[0];
    const int*   ei    = (const int*)d_in[1];
    const int*   batch = (const int*)d_in[2];
    const float* w1_1 = (const float*)d_in[3];
    const float* b1_1 = (const float*)d_in[4];
    const float* w2_1 = (const float*)d_in[5];
    const float* b2_1 = (const float*)d_in[6];
    const float* w1_2 = (const float*)d_in[7];
    const float* b1_2 = (const float*)d_in[8];
    const float* w2_2 = (const float*)d_in[9];
    const float* b2_2 = (const float*)d_in[10];
    const float* w1_3 = (const float*)d_in[11];
    const float* b1_3 = (const float*)d_in[12];
    const float* w2_3 = (const float*)d_in[13];
    const float* b2_3 = (const float*)d_in[14];
    const float* wfc  = (const float*)d_in[15];
    const float* bfc  = (const float*)d_in[16];
    float* out = (float*)d_out;

    char* ws = (char*)d_ws;
    size_t off = 0;
    auto alloc = [&](size_t bytes) {
        void* p = ws + off;
        off = (off + bytes + 255) & ~(size_t)255;
        return p;
    };
    int* deg      = (int*)alloc((size_t)NNODES * 4);
    int* cursor   = (int*)alloc((size_t)NNODES * 4);
    int* rowptr   = (int*)alloc((size_t)(NNODES + 1) * 4);
    int* bsum     = (int*)alloc(256 * 4);
    int* boff     = (int*)alloc(256 * 4);
    int* csr_src  = (int*)alloc((size_t)NEDGES * 4);
    int* csr_dst  = (int*)alloc((size_t)NEDGES * 4);
    float* U      = (float*)alloc((size_t)NNODES * 256 * 4);
    unsigned short* V = (unsigned short*)alloc((size_t)NNODES * 256 * 2);
    float* x1     = (float*)alloc((size_t)NNODES * 64 * 4);
    float* x2     = (float*)alloc((size_t)NNODES * 128 * 4);
    float* x3     = (float*)alloc((size_t)NNODES * 256 * 4);
    unsigned* poolEnc = (unsigned*)alloc((size_t)NGRAPHS * 256 * 4);
    (void)ws_size; (void)in_sizes; (void)n_in; (void)out_size;

    // CSR by dst (shared across the 3 layers)
    k_init<<<256, 256, 0, stream>>>(deg, cursor, poolEnc);
    k_count<<<NEDGES / 256, 256, 0, stream>>>(ei, deg);
    k_scan1<<<256, 256, 0, stream>>>(deg, rowptr, bsum);
    k_scan2<<<1, 256, 0, stream>>>(bsum, boff);
    k_scan3<<<256, 256, 0, stream>>>(rowptr, boff);
    k_scatter<<<NEDGES / 256, 256, 0, stream>>>(ei, rowptr, cursor, csr_src, csr_dst);

    // layer 1: F_in=3, H=64, F=64   (2x2 waves, TR=64)
    k_uv<3, 64><<<NNODES / 16, 256, 0, stream>>>(x, w1_1, b1_1, U, V);
    k_agg<64, 64, 2, 2, 4><<<NNODES / 16, 256, 0, stream>>>(U, V, w2_1, b2_1, rowptr, csr_src, csr_dst, x1);
    // layer 2: F_in=64, H=128, F=128  (1x4 waves, TR=32)
    k_uv<64, 128><<<NNODES / 16, 256, 0, stream>>>(x1, w1_2, b1_2, U, V);
    k_agg<128, 128, 1, 4, 4><<<NNODES / 16, 256, 0, stream>>>(U, V, w2_2, b2_2, rowptr, csr_src, csr_dst, x2);
    // layer 3: F_in=128, H=256, F=256  (1x8 waves, TR=32, single pass)
    k_uv<128, 256><<<NNODES / 16, 256, 0, stream>>>(x2, w1_3, b1_3, U, V);
    k_agg<256, 256, 1, 8, 4><<<NNODES / 16, 512, 0, stream>>>(U, V, w2_3, b2_3, rowptr, csr_src, csr_dst, x3);

    // global max pool + FC
    k_pool<<<dim3(NGRAPHS, 8), 256, 0, stream>>>(x3, batch, poolEnc);
    k_fc<<<NGRAPHS, 128, 0, stream>>>(poolEnc, wfc, bfc, out);
}